// Round 15
// baseline (2736.386 us; speedup 1.0000x reference)
//
#include <hip/hip_runtime.h>
#include <cstddef>
#include <cstdint>

#define THREADS 256
#define NBLK 512

typedef short bh8 __attribute__((ext_vector_type(8)));
typedef float fx4 __attribute__((ext_vector_type(4)));

__device__ __forceinline__ float bf2f(unsigned short u) {
  union { unsigned int i; float f; } x;
  x.i = ((unsigned int)u) << 16;
  return x.f;
}
__device__ __forceinline__ unsigned short f2bf(float f) {
  union { float f; unsigned int i; } x;
  x.f = f;
  unsigned int r = x.i + 0x7fffu + ((x.i >> 16) & 1u);
  return (unsigned short)(r >> 16);
}
__device__ __forceinline__ void gld16(const void* g, void* l) {
  __builtin_amdgcn_global_load_lds(
      (const __attribute__((address_space(1))) unsigned int*)g,
      (__attribute__((address_space(3))) unsigned int*)l, 16, 0, 0);
}

struct PackDesc {
  const float* W;
  unsigned short* out;
  int O, K, TW, nOt, TS;
  unsigned cum;
};

struct Args {
  const float *img, *verts;
  const int* src;
  const float* adjw;
  const float *lin0_W, *lin0_b;
  const float *b0_pre_g, *b0_pre_b, *b0_lin1_b, *b0_n1_g, *b0_n1_b, *b0_conv_b;
  const float *b0_n2_g, *b0_n2_b, *b0_lin2_b, *b0_skip_W, *b0_skip_b;
  const float *blk_pre_g, *blk_pre_b, *blk_lin1_b, *blk_n1_g, *blk_n1_b;
  const float *blk_conv_b, *blk_n2_g, *blk_n2_b, *blk_lin2_b;
  const float *h1_b, *h2_W, *h2_b, *hn_g, *hn_b, *h3_W, *h3_b;
  unsigned short *xb16, *t256a, *t256b;
  float *vbuf, *svbuf, *t64, *t32, *imgT, *wv, *m0, *r0, *mh, *rh;
  float *sA, *qA, *sv, *sq, *ub, *suT;
  unsigned short *pw_b0l1, *pw_b0cv, *pw_b0l2, *pw_b0sk, *pw_l1, *pw_cv, *pw_l2, *pw_h1;
  unsigned* bar;
  float* dout;
  PackDesc pd[8];
  unsigned grand;
  int N, NP;
};

#define OFF_B0N1 0
#define OFF_B0N2 512
__device__ __forceinline__ int off_pre(int l) { return 1024 + l * 2048; }
__device__ __forceinline__ int off_n1(int l) { return 1024 + l * 2048 + 1024; }
__device__ __forceinline__ int off_n2(int l) { return 1024 + l * 2048 + 1536; }

// device-scope grid barrier (monotonic phase counter; all blocks co-resident)
__device__ __forceinline__ void gbar(unsigned* bar, unsigned target) {
  __syncthreads();
  if (threadIdx.x == 0) {
    __threadfence();
    atomicAdd(bar, 1u);
    while (atomicAdd(bar, 0u) < target) __builtin_amdgcn_s_sleep(1);
    __threadfence();
  }
  __syncthreads();
}

// ---------------------------------------------------------------------------
// device building blocks (bodies identical to R14 kernels, coords as params)
// ---------------------------------------------------------------------------
typedef unsigned short A4T[4][128][8];

template <int XM, int RES, int OUT16, int ORELU, int STATS>
__device__ void dev_mgemm(
    unsigned short* smA, unsigned short* smB, const unsigned short* Wp,
    const float* bias, const void* Xv, const float* ub, const float* vv,
    const float* meanS, const float* rinvS, const float* gamma,
    const float* beta, const float* resA, const float* resB,
    float* sacc, float* qacc, void* outv, int O, int I, int N, int NPn,
    int bx, int by, int b) {
  A4T* Alds = (A4T*)smA;
  A4T* Blds = (A4T*)smB;
  const int tid = threadIdx.x;
  const int lane = tid & 63;
  const int wid = tid >> 6;
  const int wm = wid & 1, wn = wid >> 1;
  const int n0 = bx * 128;
  const int o0 = by * 128;
  const int K8 = I >> 3;
  const unsigned short* wp = Wp + (size_t)by * K8 * 1024;

  fx4 acc[4][4];
#pragma unroll
  for (int i = 0; i < 4; ++i)
#pragma unroll
    for (int j = 0; j < 4; ++j) {
      acc[i][j][0] = 0.f; acc[i][j][1] = 0.f;
      acc[i][j][2] = 0.f; acc[i][j][3] = 0.f;
    }

  const int sko = tid >> 6;
  const int sn = (tid & 63) * 2;
  const int mlane = lane & 15;
  const int klane = lane >> 4;

  auto dmaA = [&](int k0, int buf) {
    const unsigned short* asrc = wp + (size_t)(k0 >> 3) * 1024;
    unsigned short* ab = &Alds[buf][0][0][0];
    gld16(asrc + (size_t)tid * 8, ab + (size_t)tid * 8);
    gld16(asrc + (size_t)(tid + 256) * 8, ab + (size_t)(tid + 256) * 8);
  };
  auto dmaB4 = [&](int k0, int buf) {
    const unsigned short* xs =
        (const unsigned short*)Xv + ((size_t)b * NPn + n0) * I + k0 + wid * 8;
    unsigned short* bb = &Blds[buf][0][0][0] + (size_t)wid * 1024;
    gld16(xs + (size_t)lane * I, bb + (size_t)lane * 8);
    gld16(xs + (size_t)(lane + 64) * I, bb + 512 + (size_t)lane * 8);
  };

  uint4 br0, br1;
  float4 f00, f01, f10, f11, u01, u23;

  auto gloadB = [&](int k0) {
    const int ke = k0 + sko * 8;
    if (XM == 3) {
      const unsigned short* p =
          (const unsigned short*)Xv + ((size_t)b * NPn + n0 + sn) * I + ke;
      br0 = *(const uint4*)p;
      br1 = *(const uint4*)(p + I);
    } else if (XM == 1) {
      const float* p = vv + (size_t)(n0 + sn) * I + ke;
      f00 = *(const float4*)p;       f01 = *(const float4*)(p + 4);
      f10 = *(const float4*)(p + I); f11 = *(const float4*)(p + I + 4);
      const float* up = ub + (size_t)b * I + ke;
      u01 = *(const float4*)up;
      u23 = *(const float4*)(up + 4);
    } else if (XM == 0 || XM == 2) {
      const float* p = (const float*)Xv + ((size_t)b * NPn + n0 + sn) * I + ke;
      f00 = *(const float4*)p;       f01 = *(const float4*)(p + 4);
      f10 = *(const float4*)(p + I); f11 = *(const float4*)(p + I + 4);
    }
  };

  union H8 { unsigned short u[8]; uint4 q; };

  auto bstoreB = [&](int k0) {
    const int ke = k0 + sko * 8;
    float x0[8], x1[8];
    if (XM == 3) {
      H8 hr0, hr1;
      hr0.q = br0; hr1.q = br1;
#pragma unroll
      for (int j = 0; j < 8; ++j) {
        x0[j] = bf2f(hr0.u[j]);
        x1[j] = bf2f(hr1.u[j]);
      }
    } else {
      x0[0] = f00.x; x0[1] = f00.y; x0[2] = f00.z; x0[3] = f00.w;
      x0[4] = f01.x; x0[5] = f01.y; x0[6] = f01.z; x0[7] = f01.w;
      x1[0] = f10.x; x1[1] = f10.y; x1[2] = f10.z; x1[3] = f10.w;
      x1[4] = f11.x; x1[5] = f11.y; x1[6] = f11.z; x1[7] = f11.w;
    }
    if (XM == 1) {
      float uu[8] = {u01.x, u01.y, u01.z, u01.w, u23.x, u23.y, u23.z, u23.w};
#pragma unroll
      for (int j = 0; j < 8; ++j) { x0[j] += uu[j]; x1[j] += uu[j]; }
    }
    if (XM != 0) {
      float m_, r_;
      if (XM == 1) {
        m_ = meanS[b * K8 + (ke >> 3)];
        r_ = rinvS[b * K8 + (ke >> 3)];
      } else {
        float sfac = 1.f / (8.f * (float)N);
        float sv = meanS[b * K8 + (ke >> 3)];
        float qv = rinvS[b * K8 + (ke >> 3)];
        m_ = sv * sfac;
        r_ = rsqrtf(qv * sfac - m_ * m_ + 1e-5f);
      }
      float4 g0q = *(const float4*)(gamma + ke);
      float4 g1q = *(const float4*)(gamma + ke + 4);
      float4 e0q = *(const float4*)(beta + ke);
      float4 e1q = *(const float4*)(beta + ke + 4);
      float ga[8] = {g0q.x, g0q.y, g0q.z, g0q.w, g1q.x, g1q.y, g1q.z, g1q.w};
      float bb[8] = {e0q.x, e0q.y, e0q.z, e0q.w, e1q.x, e1q.y, e1q.z, e1q.w};
#pragma unroll
      for (int j = 0; j < 8; ++j) {
        x0[j] = fmaxf((x0[j] - m_) * r_ * ga[j] + bb[j], 0.f);
        x1[j] = fmaxf((x1[j] - m_) * r_ * ga[j] + bb[j], 0.f);
      }
    }
    H8 h0, h1;
#pragma unroll
    for (int j = 0; j < 8; ++j) {
      h0.u[j] = f2bf(x0[j]);
      h1.u[j] = f2bf(x1[j]);
    }
    *(uint4*)&Blds[0][sko][sn][0] = h0.q;
    *(uint4*)&Blds[0][sko][sn + 1][0] = h1.q;
  };

  auto compute = [&](int ab, int bb) {
    bh8 af[4], bfr[4];
#pragma unroll
    for (int mi = 0; mi < 4; ++mi)
      af[mi] = *(const bh8*)(&Alds[ab][klane][wm * 64 + mi * 16 + mlane][0]);
#pragma unroll
    for (int ni = 0; ni < 4; ++ni)
      bfr[ni] = *(const bh8*)(&Blds[bb][klane][wn * 64 + ni * 16 + mlane][0]);
#pragma unroll
    for (int mi = 0; mi < 4; ++mi)
#pragma unroll
      for (int ni = 0; ni < 4; ++ni)
        acc[mi][ni] = __builtin_amdgcn_mfma_f32_16x16x32_bf16(
            af[mi], bfr[ni], acc[mi][ni], 0, 0, 0);
  };

  if (XM == 4) {
    dmaA(0, 0);
    dmaB4(0, 0);
    __syncthreads();
    for (int k0 = 0; k0 < I; k0 += 32) {
      const int cur = (k0 >> 5) & 1;
      if (k0 + 32 < I) {
        dmaA(k0 + 32, cur ^ 1);
        dmaB4(k0 + 32, cur ^ 1);
      }
      compute(cur, cur);
      __syncthreads();
    }
  } else {
    dmaA(0, 0);
    gloadB(0);
    for (int k0 = 0; k0 < I; k0 += 32) {
      const int cur = (k0 >> 5) & 1;
      bstoreB(k0);
      __syncthreads();
      if (k0 + 32 < I) {
        dmaA(k0 + 32, cur ^ 1);
        gloadB(k0 + 32);
      }
      compute(cur, 0);
      __syncthreads();
    }
  }

  float sred[4] = {0.f, 0.f, 0.f, 0.f};
  float qred[4] = {0.f, 0.f, 0.f, 0.f};
#pragma unroll
  for (int mi = 0; mi < 4; ++mi) {
    const int o = o0 + wm * 64 + mi * 16 + klane * 4;
    if (o >= O) continue;
    float4 bi;
    if (bias) bi = *(const float4*)(bias + o);
    float4 ra;
    if (RES == 2) ra = *(const float4*)(resA + (size_t)b * O + o);
#pragma unroll
    for (int ni = 0; ni < 4; ++ni) {
      const int n = n0 + wn * 64 + ni * 16 + mlane;
      if (n >= N) continue;
      float v0 = acc[mi][ni][0], v1 = acc[mi][ni][1];
      float v2 = acc[mi][ni][2], v3 = acc[mi][ni][3];
      if (bias) { v0 += bi.x; v1 += bi.y; v2 += bi.z; v3 += bi.w; }
      size_t obase = ((size_t)b * NPn + n) * O + o;
      if (RES == 1) {
        float4 rv = *(const float4*)(resA + obase);
        v0 += rv.x; v1 += rv.y; v2 += rv.z; v3 += rv.w;
      }
      if (RES == 3) {
        ushort4 rv = *(const ushort4*)((const unsigned short*)resA + obase);
        v0 += bf2f(rv.x); v1 += bf2f(rv.y);
        v2 += bf2f(rv.z); v3 += bf2f(rv.w);
      }
      if (RES == 2) {
        float4 rb = *(const float4*)(resB + (size_t)n * O + o);
        v0 += ra.x + rb.x; v1 += ra.y + rb.y;
        v2 += ra.z + rb.z; v3 += ra.w + rb.w;
      }
      if (ORELU) {
        v0 = fmaxf(v0, 0.f); v1 = fmaxf(v1, 0.f);
        v2 = fmaxf(v2, 0.f); v3 = fmaxf(v3, 0.f);
      }
      if (STATS) {
        sred[mi] += v0 + v1 + v2 + v3;
        qred[mi] += v0 * v0 + v1 * v1 + v2 * v2 + v3 * v3;
      }
      if (OUT16) {
        ushort4 h;
        h.x = f2bf(v0); h.y = f2bf(v1); h.z = f2bf(v2); h.w = f2bf(v3);
        *(ushort4*)((unsigned short*)outv + obase) = h;
      } else {
        float4 fv; fv.x = v0; fv.y = v1; fv.z = v2; fv.w = v3;
        *(float4*)((float*)outv + obase) = fv;
      }
    }
  }
  if (STATS) {
    const int G = O >> 3;
#pragma unroll
    for (int mi = 0; mi < 4; ++mi) {
      const int o = o0 + wm * 64 + mi * 16 + klane * 4;
      if (o >= O) continue;
      float s = sred[mi], q = qred[mi];
#pragma unroll
      for (int m = 1; m < 16; m <<= 1) {
        s += __shfl_xor(s, m, 64);
        q += __shfl_xor(q, m, 64);
      }
      if (mlane == 0) {
        atomicAdd(&sacc[b * G + (o >> 3)], s);
        atomicAdd(&qacc[b * G + (o >> 3)], q);
      }
    }
  }
}

// 64x128 tile, plain-bf16 dual-DMA (h1 only: O=64)
__device__ void dev_mgemm64(
    unsigned short* smA, unsigned short* smB, const unsigned short* Wp,
    const float* bias, const unsigned short* Xv, void* outv, int O, int I,
    int N, int NPn, int bx, int b) {
  typedef unsigned short A64T[4][64][8];
  A64T* Alds = (A64T*)smA;
  A4T* Blds = (A4T*)smB;
  const int tid = threadIdx.x;
  const int lane = tid & 63;
  const int wid = tid >> 6;
  const int n0 = bx * 128;
  const int K8 = I >> 3;
  const unsigned short* wp = Wp;

  fx4 acc[4][2];
#pragma unroll
  for (int i = 0; i < 4; ++i)
#pragma unroll
    for (int j = 0; j < 2; ++j) {
      acc[i][j][0] = 0.f; acc[i][j][1] = 0.f;
      acc[i][j][2] = 0.f; acc[i][j][3] = 0.f;
    }
  const int mlane = lane & 15;
  const int klane = lane >> 4;

  auto dmaA = [&](int k0, int buf) {
    const unsigned short* asrc = wp + (size_t)(k0 >> 3) * 512;
    unsigned short* ab = &Alds[buf][0][0][0];
    gld16(asrc + (size_t)tid * 8, ab + (size_t)tid * 8);
  };
  auto dmaB = [&](int k0, int buf) {
    const unsigned short* xs = Xv + ((size_t)b * NPn + n0) * I + k0 + wid * 8;
    unsigned short* bb = &Blds[buf][0][0][0] + (size_t)wid * 1024;
    gld16(xs + (size_t)lane * I, bb + (size_t)lane * 8);
    gld16(xs + (size_t)(lane + 64) * I, bb + 512 + (size_t)lane * 8);
  };

  dmaA(0, 0);
  dmaB(0, 0);
  __syncthreads();
  for (int k0 = 0; k0 < I; k0 += 32) {
    const int cur = (k0 >> 5) & 1;
    if (k0 + 32 < I) {
      dmaA(k0 + 32, cur ^ 1);
      dmaB(k0 + 32, cur ^ 1);
    }
    bh8 af[4], bfr[2];
#pragma unroll
    for (int mi = 0; mi < 4; ++mi)
      af[mi] = *(const bh8*)(&Alds[cur][klane][mi * 16 + mlane][0]);
#pragma unroll
    for (int ni = 0; ni < 2; ++ni)
      bfr[ni] = *(const bh8*)(&Blds[cur][klane][wid * 32 + ni * 16 + mlane][0]);
#pragma unroll
    for (int mi = 0; mi < 4; ++mi)
#pragma unroll
      for (int ni = 0; ni < 2; ++ni)
        acc[mi][ni] = __builtin_amdgcn_mfma_f32_16x16x32_bf16(
            af[mi], bfr[ni], acc[mi][ni], 0, 0, 0);
    __syncthreads();
  }

#pragma unroll
  for (int mi = 0; mi < 4; ++mi) {
    const int o = mi * 16 + klane * 4;
    float4 bi = *(const float4*)(bias + o);
#pragma unroll
    for (int ni = 0; ni < 2; ++ni) {
      const int n = n0 + wid * 32 + ni * 16 + mlane;
      if (n >= N) continue;
      float v0 = acc[mi][ni][0] + bi.x, v1 = acc[mi][ni][1] + bi.y;
      float v2 = acc[mi][ni][2] + bi.z, v3 = acc[mi][ni][3] + bi.w;
      v0 = fmaxf(v0, 0.f); v1 = fmaxf(v1, 0.f);
      v2 = fmaxf(v2, 0.f); v3 = fmaxf(v3, 0.f);
      size_t obase = ((size_t)b * NPn + n) * O + o;
      float4 fv; fv.x = v0; fv.y = v1; fv.z = v2; fv.w = v3;
      *(float4*)((float*)outv + obase) = fv;
    }
  }
}

__device__ void dev_agg16(const unsigned short* Xn, const float* sarr,
                          const float* qarr, const float* gamma,
                          const float* beta, const int* src, const float* wgt,
                          unsigned short* outb, int N, int NPn, int nb, int b) {
  int w = threadIdx.x >> 6, lane = threadIdx.x & 63;
  int n = nb * 4 + w;
  if (n >= N) return;
  int c = lane * 4;
  int g = c >> 3;
  float sfac = 1.f / (8.f * (float)N);
  float svv = sarr[b * 32 + g], qv = qarr[b * 32 + g];
  float m = svv * sfac;
  float ri = rsqrtf(qv * sfac - m * m + 1e-5f);
  float4 g4 = *(const float4*)(gamma + c);
  float4 b4 = *(const float4*)(beta + c);
  const int* sp = src + n * 8;
  const float* wp = wgt + n * 8;
  const unsigned short* base = Xn + (size_t)b * NPn * 256;
  float a0 = 0.f, a1 = 0.f, a2 = 0.f, a3 = 0.f;
#pragma unroll
  for (int j = 0; j < 8; ++j) {
    int sidx = sp[j];
    float wj = wp[j];
    ushort4 x4 = *(const ushort4*)(base + (size_t)sidx * 256 + c);
    a0 = fmaf(wj, fmaxf((bf2f(x4.x) - m) * ri * g4.x + b4.x, 0.f), a0);
    a1 = fmaf(wj, fmaxf((bf2f(x4.y) - m) * ri * g4.y + b4.y, 0.f), a1);
    a2 = fmaf(wj, fmaxf((bf2f(x4.z) - m) * ri * g4.z + b4.z, 0.f), a2);
    a3 = fmaf(wj, fmaxf((bf2f(x4.w) - m) * ri * g4.w + b4.w, 0.f), a3);
  }
  ushort4 h;
  h.x = f2bf(a0); h.y = f2bf(a1); h.z = f2bf(a2); h.w = f2bf(a3);
  *(ushort4*)(outb + ((size_t)b * NPn + n) * 256 + c) = h;
}

__device__ void dev_ugemm2(const float* W, int ldw, int woff, const float* bias,
                           const float* X, float* out, int K, int Ofull,
                           int xl, int ks, int bx, int byy) {
  int tid = threadIdx.x;
  int b = tid & 15, cl = tid >> 4;
  int c = bx * 16 + cl;
  int k0 = byy * ks, k1 = k0 + ks;
  const float* wr = W + woff + (size_t)c * ldw;
  float a0 = 0.f, a1 = 0.f;
  if (xl) {
    const float* xr = X + (size_t)b * K;
    for (int k = k0; k < k1; k += 2) {
      a0 = fmaf(wr[k], xr[k], a0);
      a1 = fmaf(wr[k + 1], xr[k + 1], a1);
    }
  } else {
    for (int k = k0; k < k1; k += 2) {
      a0 = fmaf(wr[k], X[k * 16 + b], a0);
      a1 = fmaf(wr[k + 1], X[(k + 1) * 16 + b], a1);
    }
  }
  float r = a0 + a1;
  if (byy == 0) r += bias[c];
  atomicAdd(&out[(size_t)b * Ofull + c], r);
}

__device__ void dev_stats_head(const float* X, float* mean, float* rinv,
                               int NPn, int N, int j) {
  __shared__ float shs[4], shq[4];
  int b = j >> 2, g = j & 3;
  int c = g * 8 + (threadIdx.x & 7);
  float s = 0.f, q = 0.f;
  for (int n = threadIdx.x >> 3; n < N; n += 32) {
    float x = X[((size_t)b * NPn + n) * 32 + c];
    s += x; q += x * x;
  }
#pragma unroll
  for (int off = 32; off; off >>= 1) {
    s += __shfl_down(s, off, 64);
    q += __shfl_down(q, off, 64);
  }
  int wv = threadIdx.x >> 6;
  if ((threadIdx.x & 63) == 0) { shs[wv] = s; shq[wv] = q; }
  __syncthreads();
  if (threadIdx.x == 0) {
    s = shs[0] + shs[1] + shs[2] + shs[3];
    q = shq[0] + shq[1] + shq[2] + shq[3];
    float inv = 1.f / (8.f * (float)N);
    float m = s * inv;
    float var = q * inv - m * m;
    mean[j] = m;
    rinv[j] = rsqrtf(var + 1e-5f);
  }
  __syncthreads();
}

// ---------------------------------------------------------------------------
__global__ __launch_bounds__(THREADS, 2) void mega_k(Args a) {
  __shared__ unsigned short smA[2 * 4 * 128 * 8];
  __shared__ unsigned short smB[2 * 4 * 128 * 8];
  const int tid = threadIdx.x;
  const int N = a.N, NP = a.NP;
  const unsigned stride = gridDim.x * THREADS;
  unsigned tgt = 0;
  auto BAR = [&]() { tgt += gridDim.x; gbar(a.bar, tgt); };

  // ---- P0: weight packing + img transpose + wv pack ----
  for (unsigned e = blockIdx.x * THREADS + tid; e < a.grand; e += stride) {
    int s = 0;
#pragma unroll
    for (int i = 1; i < 8; ++i)
      if (e >= a.pd[i].cum) s = i;
#pragma unroll
    for (int i = 0; i < 8; ++i) {
      if (s != i) continue;
      const float* W = a.pd[i].W;
      int O = a.pd[i].O, K = a.pd[i].K, TW = a.pd[i].TW, nOt = a.pd[i].nOt;
      int TS = a.pd[i].TS;
      unsigned g = e - a.pd[i].cum;
      int j = (int)(g & 7);
      int m;
      unsigned rest;
      if (TS == 128) { m = (int)((g >> 3) & 127); rest = g >> 10; }
      else { m = (int)((g >> 3) & 63); rest = g >> 9; }
      int K8 = K >> 3;
      int kg = (int)(rest % (unsigned)K8);
      unsigned rest2 = rest / (unsigned)K8;
      int ot = (int)(rest2 % (unsigned)nOt);
      int l = (int)(rest2 / (unsigned)nOt);
      int o = ot * TS + m, k = kg * 8 + j;
      float val = 0.f;
      if (o < O)
        val = TW ? W[(size_t)l * O * K + (size_t)k * O + o]
                 : W[(size_t)l * O * K + (size_t)o * K + k];
      a.pd[i].out[g] = f2bf(val);
    }
  }
  for (unsigned g = blockIdx.x * THREADS + tid; g < 2048u * 16u; g += stride) {
    int k = g >> 4, b = g & 15;
    a.imgT[k * 16 + b] = a.img[b * 2048 + k];
  }
  for (unsigned g = blockIdx.x * THREADS + tid; g < 3072u; g += stride) {
    int k = g >> 10, c = g & 1023;
    a.wv[g] = a.lin0_W[(size_t)c * 2051 + k];
  }
  BAR();
  // ---- P1: lin0 u-GEMM + vertproj ----
  for (int j = blockIdx.x; j < 1024; j += gridDim.x)
    dev_ugemm2(a.lin0_W, 2051, 3, a.lin0_b, a.imgT, a.ub, 2048, 1024, 0, 128,
               j & 63, j >> 6);
  for (unsigned g = blockIdx.x * THREADS + tid; g < (unsigned)N * 1024u; g += stride) {
    int c = g & 1023, n = g >> 10;
    a.vbuf[(size_t)n * 1024 + c] = a.wv[c] * a.verts[n] +
                                   a.wv[1024 + c] * a.verts[N + n] +
                                   a.wv[2048 + c] * a.verts[2 * N + n];
  }
  BAR();
  // ---- P2: vstats ----
  for (int j = blockIdx.x; j < 64; j += gridDim.x) {
    int c = (j & 3) * THREADS + tid;
    int y = j >> 2;
    float s = 0.f, q = 0.f;
    for (int n = y; n < N; n += 16) {
      float x = a.vbuf[(size_t)n * 1024 + c];
      s += x; q += x * x;
    }
    atomicAdd(&a.sv[c], s);
    atomicAdd(&a.sq[c], q);
  }
  BAR();
  // ---- P3: combine_b0 ----
  for (unsigned g = blockIdx.x * THREADS + tid; g < 2048u; g += stride) {
    int b = g >> 7, gg = g & 127;
    int c0 = gg * 8;
    float fN = (float)N;
    float s = 0.f, q = 0.f;
#pragma unroll
    for (int j = 0; j < 8; ++j) {
      float u = a.ub[b * 1024 + c0 + j];
      float svc = a.sv[c0 + j];
      s += fN * u + svc;
      q += fN * u * u + 2.f * u * svc + a.sq[c0 + j];
    }
    float inv = 1.f / (8.f * fN);
    float m = s * inv;
    float var = q * inv - m * m;
    a.m0[g] = m;
    a.r0[g] = rsqrtf(var + 1e-5f);
  }
  BAR();
  // ---- P4: b0 lin1 + b0 skip (svbuf gemm + u-gemm) ----
  for (int j = blockIdx.x; j < 760; j += gridDim.x) {
    if (j < 448) {
      dev_mgemm<1, 0, 1, 0, 1>(smA, smB, a.pw_b0l1, a.b0_lin1_b, nullptr, a.ub,
                               a.vbuf, a.m0, a.r0, a.b0_pre_g, a.b0_pre_b,
                               nullptr, nullptr, a.sA + OFF_B0N1,
                               a.qA + OFF_B0N1, a.t256a, 256, 1024, N, NP,
                               j % 14, (j / 14) % 2, j / 28);
    } else if (j < 504) {
      int k = j - 448;
      dev_mgemm<0, 0, 0, 0, 0>(smA, smB, a.pw_b0sk, nullptr, a.vbuf, nullptr,
                               nullptr, nullptr, nullptr, nullptr, nullptr,
                               nullptr, nullptr, nullptr, nullptr, a.svbuf,
                               512, 1024, N, NP, k % 14, k / 14, 0);
    } else {
      int k = j - 504;
      dev_ugemm2(a.b0_skip_W, 1024, 0, a.b0_skip_b, a.ub, a.suT, 1024, 512, 1,
                 128, k & 31, k >> 5);
    }
  }
  BAR();
  const int NB4 = (N + 3) >> 2;
  // ---- P5: b0 agg ----
  for (int j = blockIdx.x; j < NB4 * 16; j += gridDim.x)
    dev_agg16(a.t256a, a.sA + OFF_B0N1, a.qA + OFF_B0N1, a.b0_n1_g, a.b0_n1_b,
              a.src, a.adjw, a.t256b, N, NP, j % NB4, j / NB4);
  BAR();
  // ---- P6: b0 conv ----
  for (int j = blockIdx.x; j < 448; j += gridDim.x)
    dev_mgemm<4, 0, 1, 0, 1>(smA, smB, a.pw_b0cv, a.b0_conv_b, a.t256b,
                             nullptr, nullptr, nullptr, nullptr, nullptr,
                             nullptr, nullptr, nullptr, a.sA + OFF_B0N2,
                             a.qA + OFF_B0N2, a.t256a, 256, 256, N, NP, j % 14,
                             (j / 14) % 2, j / 28);
  BAR();
  // ---- P7: b0 lin2 ----
  for (int j = blockIdx.x; j < 896; j += gridDim.x)
    dev_mgemm<3, 2, 1, 0, 1>(smA, smB, a.pw_b0l2, a.b0_lin2_b, a.t256a,
                             nullptr, nullptr, a.sA + OFF_B0N2,
                             a.qA + OFF_B0N2, a.b0_n2_g, a.b0_n2_b, a.suT,
                             a.svbuf, a.sA + off_pre(0), a.qA + off_pre(0),
                             a.xb16, 512, 256, N, NP, j % 14, (j / 14) % 4,
                             j / 56);
  BAR();
  // ---- blocks 1..5 ----
  for (int l = 0; l < 5; ++l) {
    const float* pg = a.blk_pre_g + l * 512;
    const float* pb = a.blk_pre_b + l * 512;
    const unsigned short* l1W = a.pw_l1 + (size_t)l * 131072;
    const float* l1b = a.blk_lin1_b + l * 256;
    const float* n1g = a.blk_n1_g + l * 256;
    const float* n1b = a.blk_n1_b + l * 256;
    const unsigned short* cW = a.pw_cv + (size_t)l * 65536;
    const float* cb = a.blk_conv_b + l * 256;
    const float* n2g = a.blk_n2_g + l * 256;
    const float* n2b = a.blk_n2_b + l * 256;
    const unsigned short* l2W = a.pw_l2 + (size_t)l * 131072;
    const float* l2b = a.blk_lin2_b + l * 512;

    for (int j = blockIdx.x; j < 448; j += gridDim.x)
      dev_mgemm<3, 0, 1, 0, 1>(smA, smB, l1W, l1b, a.xb16, nullptr, nullptr,
                               a.sA + off_pre(l), a.qA + off_pre(l), pg, pb,
                               nullptr, nullptr, a.sA + off_n1(l),
                               a.qA + off_n1(l), a.t256a, 256, 512, N, NP,
                               j % 14, (j / 14) % 2, j / 28);
    BAR();
    for (int j = blockIdx.x; j < NB4 * 16; j += gridDim.x)
      dev_agg16(a.t256a, a.sA + off_n1(l), a.qA + off_n1(l), n1g, n1b, a.src,
                a.adjw, a.t256b, N, NP, j % NB4, j / NB4);
    BAR();
    for (int j = blockIdx.x; j < 448; j += gridDim.x)
      dev_mgemm<4, 0, 1, 0, 1>(smA, smB, cW, cb, a.t256b, nullptr, nullptr,
                               nullptr, nullptr, nullptr, nullptr, nullptr,
                               nullptr, a.sA + off_n2(l), a.qA + off_n2(l),
                               a.t256a, 256, 256, N, NP, j % 14, (j / 14) % 2,
                               j / 28);
    BAR();
    if (l < 4) {
      for (int j = blockIdx.x; j < 896; j += gridDim.x)
        dev_mgemm<3, 3, 1, 0, 1>(smA, smB, l2W, l2b, a.t256a, nullptr, nullptr,
                                 a.sA + off_n2(l), a.qA + off_n2(l), n2g, n2b,
                                 (const float*)a.xb16, nullptr,
                                 a.sA + off_pre(l + 1), a.qA + off_pre(l + 1),
                                 a.xb16, 512, 256, N, NP, j % 14, (j / 14) % 4,
                                 j / 56);
    } else {
      for (int j = blockIdx.x; j < 896; j += gridDim.x)
        dev_mgemm<3, 3, 1, 0, 0>(smA, smB, l2W, l2b, a.t256a, nullptr, nullptr,
                                 a.sA + off_n2(l), a.qA + off_n2(l), n2g, n2b,
                                 (const float*)a.xb16, nullptr, nullptr,
                                 nullptr, a.xb16, 512, 256, N, NP, j % 14,
                                 (j / 14) % 4, j / 56);
    }
    BAR();
  }
  // ---- head ----
  for (int j = blockIdx.x; j < 224; j += gridDim.x)
    dev_mgemm64(smA, smB, a.pw_h1, a.h1_b, a.xb16, a.t64, 64, 512, N, NP,
                j % 14, j / 14);
  BAR();
  const int GX2 = (N * 32 + THREADS - 1) / THREADS;
  for (int j = blockIdx.x; j < GX2 * 16; j += gridDim.x) {
    int gid = (j % GX2) * THREADS + tid;
    int o = gid & 31, n = gid >> 5;
    if (n >= N) continue;
    int b = j / GX2;
    const float* xr = a.t64 + ((size_t)b * NP + n) * 64;
    const float* wr = a.h2_W + o * 64;
    float acc = a.h2_b[o];
#pragma unroll
    for (int i = 0; i < 64; i += 4) {
      float4 w4 = *(const float4*)(wr + i);
      float4 x4 = *(const float4*)(xr + i);
      acc += w4.x * x4.x + w4.y * x4.y + w4.z * x4.z + w4.w * x4.w;
    }
    a.t32[((size_t)b * NP + n) * 32 + o] = acc;
  }
  BAR();
  for (int j = blockIdx.x; j < 64; j += gridDim.x)
    dev_stats_head(a.t32, a.mh, a.rh, NP, N, j);
  BAR();
  const int GX3 = (N + THREADS - 1) / THREADS;
  for (int j = blockIdx.x; j < GX3 * 16; j += gridDim.x) {
    int n = (j % GX3) * THREADS + tid;
    if (n >= N) continue;
    int b = j / GX3;
    const float* xr = a.t32 + ((size_t)b * NP + n) * 32;
    float y0 = a.h3_b[0], y1 = a.h3_b[1], y2 = a.h3_b[2];
#pragma unroll
    for (int c = 0; c < 32; ++c) {
      float m = a.mh[b * 4 + (c >> 3)], ri = a.rh[b * 4 + (c >> 3)];
      float x = fmaxf((xr[c] - m) * ri * a.hn_g[c] + a.hn_b[c], 0.f);
      y0 = fmaf(a.h3_W[c], x, y0);
      y1 = fmaf(a.h3_W[32 + c], x, y1);
      y2 = fmaf(a.h3_W[64 + c], x, y2);
    }
    a.dout[(size_t)b * 3 * N + n] = y0;
    a.dout[(size_t)b * 3 * N + N + n] = y1;
    a.dout[(size_t)b * 3 * N + 2 * N + n] = y2;
  }
}

// ---------------------------------------------------------------------------
extern "C" void kernel_launch(void* const* d_in, const int* in_sizes, int n_in,
                              void* d_out, int out_size, void* d_ws,
                              size_t ws_size, hipStream_t stream) {
  (void)n_in; (void)out_size; (void)ws_size;
  Args a;
  a.img = (const float*)d_in[0];
  a.verts = (const float*)d_in[1];
  a.src = (const int*)d_in[2];
  a.adjw = (const float*)d_in[4];
  a.lin0_W = (const float*)d_in[5];
  a.lin0_b = (const float*)d_in[6];
  a.b0_pre_g = (const float*)d_in[7];
  a.b0_pre_b = (const float*)d_in[8];
  const float* b0_lin1_W = (const float*)d_in[9];
  a.b0_lin1_b = (const float*)d_in[10];
  a.b0_n1_g = (const float*)d_in[11];
  a.b0_n1_b = (const float*)d_in[12];
  const float* b0_conv_W = (const float*)d_in[13];
  a.b0_conv_b = (const float*)d_in[14];
  a.b0_n2_g = (const float*)d_in[15];
  a.b0_n2_b = (const float*)d_in[16];
  const float* b0_lin2_W = (const float*)d_in[17];
  a.b0_lin2_b = (const float*)d_in[18];
  a.b0_skip_W = (const float*)d_in[19];
  a.b0_skip_b = (const float*)d_in[20];
  a.blk_pre_g = (const float*)d_in[21];
  a.blk_pre_b = (const float*)d_in[22];
  const float* blk_lin1_W = (const float*)d_in[23];
  a.blk_lin1_b = (const float*)d_in[24];
  a.blk_n1_g = (const float*)d_in[25];
  a.blk_n1_b = (const float*)d_in[26];
  const float* blk_conv_W = (const float*)d_in[27];
  a.blk_conv_b = (const float*)d_in[28];
  a.blk_n2_g = (const float*)d_in[29];
  a.blk_n2_b = (const float*)d_in[30];
  const float* blk_lin2_W = (const float*)d_in[31];
  a.blk_lin2_b = (const float*)d_in[32];
  const float* h1_W = (const float*)d_in[33];
  a.h1_b = (const float*)d_in[34];
  a.h2_W = (const float*)d_in[35];
  a.h2_b = (const float*)d_in[36];
  a.hn_g = (const float*)d_in[37];
  a.hn_b = (const float*)d_in[38];
  a.h3_W = (const float*)d_in[39];
  a.h3_b = (const float*)d_in[40];

  const int N = in_sizes[1] / 3;
  const int NP = ((N + 127) / 128) * 128;
  const int B = 16;
  a.N = N;
  a.NP = NP;
  a.dout = (float*)d_out;

  char* wsb = (char*)d_ws;
  size_t off = 0;
  auto alloc = [&](size_t nbytes) {
    void* p = wsb + off;
    off += (nbytes + 255) & ~(size_t)255;
    return p;
  };
  a.xb16 = (unsigned short*)alloc((size_t)B * NP * 512 * 2);
  a.t256a = (unsigned short*)alloc((size_t)B * NP * 256 * 2);
  a.t256b = (unsigned short*)alloc((size_t)B * NP * 256 * 2);
  a.vbuf = (float*)alloc((size_t)NP * 1024 * 4);
  a.svbuf = (float*)alloc((size_t)NP * 512 * 4);
  a.t64 = (float*)alloc((size_t)B * NP * 64 * 4);
  a.t32 = (float*)alloc((size_t)B * NP * 32 * 4);
  a.imgT = (float*)alloc(2048 * 16 * 4);
  a.wv = (float*)alloc(3 * 1024 * 4);
  a.m0 = (float*)alloc(2048 * 4);
  a.r0 = (float*)alloc(2048 * 4);
  a.mh = (float*)alloc(64 * 4);
  a.rh = (float*)alloc(64 * 4);
  // zero region: sA/qA + sv/sq + ub + suT + barrier counter
  float* zerobuf = (float*)alloc((size_t)49408 * 4);
  a.sA = zerobuf;
  a.qA = zerobuf + 11264;
  a.sv = zerobuf + 22528;
  a.sq = zerobuf + 23552;
  a.ub = zerobuf + 24576;
  a.suT = zerobuf + 40960;
  a.bar = (unsigned*)(zerobuf + 49152);
  a.pw_b0l1 = (unsigned short*)alloc(262144 * 2);
  a.pw_b0cv = (unsigned short*)alloc(65536 * 2);
  a.pw_b0l2 = (unsigned short*)alloc(131072 * 2);
  a.pw_b0sk = (unsigned short*)alloc(524288 * 2);
  a.pw_l1 = (unsigned short*)alloc(655360 * 2);
  a.pw_cv = (unsigned short*)alloc(327680 * 2);
  a.pw_l2 = (unsigned short*)alloc(655360 * 2);
  a.pw_h1 = (unsigned short*)alloc(32768 * 2);

  {
    unsigned c = 0;
    auto set = [&](int i, const float* W, unsigned short* o, int O, int K,
                   int TW, int nOt, int TS, unsigned tot) {
      a.pd[i] = {W, o, O, K, TW, nOt, TS, c};
      c += tot;
    };
    set(0, b0_lin1_W, a.pw_b0l1, 256, 1024, 0, 2, 128, 262144);
    set(1, b0_conv_W, a.pw_b0cv, 256, 256, 1, 2, 128, 65536);
    set(2, b0_lin2_W, a.pw_b0l2, 512, 256, 0, 4, 128, 131072);
    set(3, a.b0_skip_W, a.pw_b0sk, 512, 1024, 0, 4, 128, 524288);
    set(4, blk_lin1_W, a.pw_l1, 256, 512, 0, 2, 128, 655360);
    set(5, blk_conv_W, a.pw_cv, 256, 256, 1, 2, 128, 327680);
    set(6, blk_lin2_W, a.pw_l2, 512, 256, 0, 4, 128, 655360);
    set(7, h1_W, a.pw_h1, 64, 512, 0, 1, 64, 32768);
    a.grand = c;
  }

  hipMemsetAsync(zerobuf, 0, (size_t)49408 * 4, stream);
  mega_k<<<NBLK, THREADS, 0, stream>>>(a);
}

// Round 16
// 1325.586 us; speedup vs baseline: 2.0643x; 2.0643x over previous
//
#include <hip/hip_runtime.h>
#include <cstddef>
#include <cstdint>

#define THREADS 256

typedef short bh8 __attribute__((ext_vector_type(8)));
typedef float fx4 __attribute__((ext_vector_type(4)));

__device__ __forceinline__ float bf2f(unsigned short u) {
  union { unsigned int i; float f; } x;
  x.i = ((unsigned int)u) << 16;
  return x.f;
}
__device__ __forceinline__ unsigned short f2bf(float f) {
  union { float f; unsigned int i; } x;
  x.f = f;
  unsigned int r = x.i + 0x7fffu + ((x.i >> 16) & 1u);
  return (unsigned short)(r >> 16);
}

// async global->LDS 16B per lane; lds dest must be wave-uniform base + lane*16
__device__ __forceinline__ void gld16(const void* g, void* l) {
  __builtin_amdgcn_global_load_lds(
      (const __attribute__((address_space(1))) unsigned int*)g,
      (__attribute__((address_space(3))) unsigned int*)l, 16, 0, 0);
}

// ---------------------------------------------------------------------------
// prep kernels
// ---------------------------------------------------------------------------
__global__ __launch_bounds__(THREADS) void transpose_img_k(
    const float* __restrict__ img, float* __restrict__ imgT) {
  int gid = blockIdx.x * THREADS + threadIdx.x;
  if (gid >= 2048 * 16) return;
  int k = gid >> 4, b = gid & 15;
  imgT[k * 16 + b] = img[b * 2048 + k];
}

// wv[k][c] = lin0_W[c][k], k<3
__global__ __launch_bounds__(THREADS) void pack_wv_k(
    const float* __restrict__ W, float* __restrict__ wv) {
  int gid = blockIdx.x * THREADS + threadIdx.x;
  if (gid >= 3 * 1024) return;
  int k = gid >> 10, c = gid & 1023;
  wv[gid] = W[(size_t)c * 2051 + k];
}

// v[n][c] = sum_k wv[k][c] * verts[k][n]
__global__ __launch_bounds__(THREADS) void vertproj_k(
    const float* __restrict__ wv, const float* __restrict__ verts,
    float* __restrict__ v, int N) {
  int gid = blockIdx.x * THREADS + threadIdx.x;
  int c = gid & 1023, n = gid >> 10;
  if (n >= N) return;
  v[(size_t)n * 1024 + c] =
      wv[c] * verts[n] + wv[1024 + c] * verts[N + n] + wv[2048 + c] * verts[2 * N + n];
}

// K-split skinny GEMM: out[b][c] += slice sum; out must be pre-zeroed.
// xl=0: X[k*16+b] ; xl=1: X[b*K+k]
__global__ __launch_bounds__(THREADS) void ugemm2_k(
    const float* __restrict__ W, int ldw, int woff,
    const float* __restrict__ bias, const float* __restrict__ X,
    float* __restrict__ out, int K, int Ofull, int xl, int ks) {
  int tid = threadIdx.x;
  int b = tid & 15, cl = tid >> 4;
  int c = blockIdx.x * 16 + cl;
  int k0 = blockIdx.y * ks, k1 = k0 + ks;
  const float* wr = W + woff + (size_t)c * ldw;
  float a0 = 0.f, a1 = 0.f;
  if (xl) {
    const float* xr = X + (size_t)b * K;
    for (int k = k0; k < k1; k += 2) {
      a0 = fmaf(wr[k], xr[k], a0);
      a1 = fmaf(wr[k + 1], xr[k + 1], a1);
    }
  } else {
    for (int k = k0; k < k1; k += 2) {
      a0 = fmaf(wr[k], X[k * 16 + b], a0);
      a1 = fmaf(wr[k + 1], X[(k + 1) * 16 + b], a1);
    }
  }
  float r = a0 + a1;
  if (blockIdx.y == 0) r += bias[c];
  atomicAdd(&out[(size_t)b * Ofull + c], r);
}

// ---------------------------------------------------------------------------
// merged weight packing: W (O,K) [or (K,O) if TW] fp32 -> bf16 tiles
// [l][ot][K8][128][8]  (128-o tiles)
// ---------------------------------------------------------------------------
struct PackDesc {
  const float* W;
  unsigned short* out;
  int O, K, TW, nOt;
  unsigned cum;
};
struct PackArgs {
  PackDesc d[8];
  unsigned grand;
};

__global__ __launch_bounds__(THREADS) void packall_k(PackArgs a) {
  unsigned gid = blockIdx.x * THREADS + threadIdx.x;
  if (gid >= a.grand) return;
  int s = 0;
#pragma unroll
  for (int i = 1; i < 8; ++i)
    if (gid >= a.d[i].cum) s = i;
#pragma unroll
  for (int i = 0; i < 8; ++i) {
    if (s != i) continue;
    const float* W = a.d[i].W;
    int O = a.d[i].O, K = a.d[i].K, TW = a.d[i].TW, nOt = a.d[i].nOt;
    unsigned e = gid - a.d[i].cum;
    int j = (int)(e & 7);
    int m = (int)((e >> 3) & 127);
    unsigned rest = e >> 10;
    int K8 = K >> 3;
    int kg = (int)(rest % (unsigned)K8);
    unsigned rest2 = rest / (unsigned)K8;
    int ot = (int)(rest2 % (unsigned)nOt);
    int l = (int)(rest2 / (unsigned)nOt);
    int o = ot * 128 + m, k = kg * 8 + j;
    float val = 0.f;
    if (o < O)
      val = TW ? W[(size_t)l * O * K + (size_t)k * O + o]
               : W[(size_t)l * O * K + (size_t)o * K + k];
    a.d[i].out[e] = f2bf(val);
  }
}

// per-channel column sums of vbuf [n][1024]
__global__ __launch_bounds__(THREADS) void vstats_k(
    const float* __restrict__ v, float* __restrict__ sv,
    float* __restrict__ sq, int N) {
  int c = blockIdx.x * THREADS + threadIdx.x;
  float s = 0.f, q = 0.f;
  for (int n = blockIdx.y; n < N; n += 16) {
    float x = v[(size_t)n * 1024 + c];
    s += x; q += x * x;
  }
  atomicAdd(&sv[c], s);
  atomicAdd(&sq[c], q);
}

// b0 pre-GN mean/rinv from u[b][c] and per-c sums of v
__global__ __launch_bounds__(THREADS) void combine_b0_k(
    const float* __restrict__ ub, const float* __restrict__ sv,
    const float* __restrict__ sq, float* __restrict__ mean,
    float* __restrict__ rinv, int N) {
  int bg = blockIdx.x * THREADS + threadIdx.x;
  if (bg >= 2048) return;
  int b = bg >> 7, g = bg & 127;
  int c0 = g * 8;
  float fN = (float)N;
  float s = 0.f, q = 0.f;
#pragma unroll
  for (int j = 0; j < 8; ++j) {
    float u = ub[b * 1024 + c0 + j];
    float svc = sv[c0 + j];
    s += fN * u + svc;
    q += fN * u * u + 2.f * u * svc + sq[c0 + j];
  }
  float inv = 1.f / (8.f * fN);
  float m = s * inv;
  float var = q * inv - m * m;
  mean[bg] = m;
  rinv[bg] = rsqrtf(var + 1e-5f);
}

// ---------------------------------------------------------------------------
// graph aggregation, [b][n][256] bf16, GN(s/ss)+relu fused; wave per vertex
// ---------------------------------------------------------------------------
__global__ __launch_bounds__(THREADS) void agg16_k(
    const unsigned short* __restrict__ Xn, const float* __restrict__ sarr,
    const float* __restrict__ qarr, const float* __restrict__ gamma,
    const float* __restrict__ beta, const int* __restrict__ src,
    const float* __restrict__ wgt, unsigned short* __restrict__ outb, int N,
    int NPn) {
  int w = threadIdx.x >> 6, lane = threadIdx.x & 63;
  int n = blockIdx.x * 4 + w;
  if (n >= N) return;
  int b = blockIdx.y;
  int c = lane * 4;
  int g = c >> 3;
  float sfac = 1.f / (8.f * (float)N);
  float svv = sarr[b * 32 + g], qv = qarr[b * 32 + g];
  float m = svv * sfac;
  float ri = rsqrtf(qv * sfac - m * m + 1e-5f);
  float4 g4 = *(const float4*)(gamma + c);
  float4 b4 = *(const float4*)(beta + c);
  const int* sp = src + n * 8;
  const float* wp = wgt + n * 8;
  const unsigned short* base = Xn + (size_t)b * NPn * 256;
  float a0 = 0.f, a1 = 0.f, a2 = 0.f, a3 = 0.f;
#pragma unroll
  for (int j = 0; j < 8; ++j) {
    int sidx = sp[j];
    float wj = wp[j];
    ushort4 x4 = *(const ushort4*)(base + (size_t)sidx * 256 + c);
    a0 = fmaf(wj, fmaxf((bf2f(x4.x) - m) * ri * g4.x + b4.x, 0.f), a0);
    a1 = fmaf(wj, fmaxf((bf2f(x4.y) - m) * ri * g4.y + b4.y, 0.f), a1);
    a2 = fmaf(wj, fmaxf((bf2f(x4.z) - m) * ri * g4.z + b4.z, 0.f), a2);
    a3 = fmaf(wj, fmaxf((bf2f(x4.w) - m) * ri * g4.w + b4.w, 0.f), a3);
  }
  ushort4 h;
  h.x = f2bf(a0); h.y = f2bf(a1); h.z = f2bf(a2); h.w = f2bf(a3);
  *(ushort4*)(outb + ((size_t)b * NPn + n) * 256 + c) = h;
}

// ---------------------------------------------------------------------------
// MFMA bf16 GEMM, 128x128 tiles, BK=32, out[b][n][o]
// A staged via global_load_lds DMA, double-buffered (all XM).
// XM==4 (plain bf16): B also full-DMA double-buffered.
// XM: 0 fp32 | 1 b0 (ub+vv fp32, mean/rinv GN) | 2 fp32+s/ss GN
//     3 bf16+s/ss GN | 4 plain bf16
// RES: 0 none | 1 +resA[b][n][o] fp32 | 2 +resA[b][o]+resB[n][o] fp32
//     3 +resA[b][n][o] bf16 (resA reinterpreted as ushort)
// STATS: fused GN sum/sumsq atomics per (b, o-group)
// ---------------------------------------------------------------------------
template <int XM, int RES, int OUT16, int ORELU, int STATS>
__global__ __launch_bounds__(THREADS) void mgemm_k(
    const unsigned short* __restrict__ Wp, const float* __restrict__ bias,
    const void* __restrict__ Xv, const float* __restrict__ ub,
    const float* __restrict__ vv, const float* __restrict__ meanS,
    const float* __restrict__ rinvS, const float* __restrict__ gamma,
    const float* __restrict__ beta, const float* __restrict__ resA,
    const float* __restrict__ resB, float* __restrict__ sacc,
    float* __restrict__ qacc, void* __restrict__ outv, int O, int I, int N,
    int NPn) {
  constexpr int BBUF = (XM == 4) ? 2 : 1;
  __shared__ unsigned short Alds[2][4][128][8];     // 16KB (double-buffered DMA)
  __shared__ unsigned short Blds[BBUF][4][128][8];  // 8/16KB
  const int tid = threadIdx.x;
  const int lane = tid & 63;
  const int wid = tid >> 6;
  const int wm = wid & 1, wn = wid >> 1;
  const int n0 = blockIdx.x * 128;
  const int o0 = blockIdx.y * 128;
  const int b = blockIdx.z;
  const int K8 = I >> 3;
  const unsigned short* wp = Wp + (size_t)blockIdx.y * K8 * 1024;

  fx4 acc[4][4];
#pragma unroll
  for (int i = 0; i < 4; ++i)
#pragma unroll
    for (int j = 0; j < 4; ++j) {
      acc[i][j][0] = 0.f; acc[i][j][1] = 0.f;
      acc[i][j][2] = 0.f; acc[i][j][3] = 0.f;
    }

  const int sko = tid >> 6;
  const int sn = (tid & 63) * 2;
  const int mlane = lane & 15;
  const int klane = lane >> 4;

  // ---- A staging: async DMA of 8KB packed-W chunk ----
  auto dmaA = [&](int k0, int buf) {
    const unsigned short* asrc = wp + (size_t)(k0 >> 3) * 1024;
    unsigned short* ab = &Alds[buf][0][0][0];
    gld16(asrc + (size_t)tid * 8, ab + (size_t)tid * 8);
    gld16(asrc + (size_t)(tid + 256) * 8, ab + (size_t)(tid + 256) * 8);
  };
  auto dmaB4 = [&](int k0, int buf) {
    const unsigned short* xs =
        (const unsigned short*)Xv + ((size_t)b * NPn + n0) * I + k0 + wid * 8;
    unsigned short* bb = &Blds[buf][0][0][0] + (size_t)wid * 1024;
    gld16(xs + (size_t)lane * I, bb + (size_t)lane * 8);
    gld16(xs + (size_t)(lane + 64) * I, bb + 512 + (size_t)lane * 8);
  };

  uint4 br0, br1;
  float4 f00, f01, f10, f11, u01, u23;

  auto gloadB = [&](int k0) {
    const int ke = k0 + sko * 8;
    if (XM == 3) {
      const unsigned short* p =
          (const unsigned short*)Xv + ((size_t)b * NPn + n0 + sn) * I + ke;
      br0 = *(const uint4*)p;
      br1 = *(const uint4*)(p + I);
    } else if (XM == 1) {
      const float* p = vv + (size_t)(n0 + sn) * I + ke;
      f00 = *(const float4*)p;       f01 = *(const float4*)(p + 4);
      f10 = *(const float4*)(p + I); f11 = *(const float4*)(p + I + 4);
      const float* up = ub + (size_t)b * I + ke;
      u01 = *(const float4*)up;
      u23 = *(const float4*)(up + 4);
    } else if (XM == 0 || XM == 2) {
      const float* p = (const float*)Xv + ((size_t)b * NPn + n0 + sn) * I + ke;
      f00 = *(const float4*)p;       f01 = *(const float4*)(p + 4);
      f10 = *(const float4*)(p + I); f11 = *(const float4*)(p + I + 4);
    }
  };

  union H8 { unsigned short u[8]; uint4 q; };

  auto bstoreB = [&](int k0) {
    const int ke = k0 + sko * 8;
    float x0[8], x1[8];
    if (XM == 3) {
      H8 hr0, hr1;
      hr0.q = br0; hr1.q = br1;
#pragma unroll
      for (int j = 0; j < 8; ++j) {
        x0[j] = bf2f(hr0.u[j]);
        x1[j] = bf2f(hr1.u[j]);
      }
    } else {
      x0[0] = f00.x; x0[1] = f00.y; x0[2] = f00.z; x0[3] = f00.w;
      x0[4] = f01.x; x0[5] = f01.y; x0[6] = f01.z; x0[7] = f01.w;
      x1[0] = f10.x; x1[1] = f10.y; x1[2] = f10.z; x1[3] = f10.w;
      x1[4] = f11.x; x1[5] = f11.y; x1[6] = f11.z; x1[7] = f11.w;
    }
    if (XM == 1) {
      float uu[8] = {u01.x, u01.y, u01.z, u01.w, u23.x, u23.y, u23.z, u23.w};
#pragma unroll
      for (int j = 0; j < 8; ++j) { x0[j] += uu[j]; x1[j] += uu[j]; }
    }
    if (XM != 0) {
      float m_, r_;
      if (XM == 1) {
        m_ = meanS[b * K8 + (ke >> 3)];
        r_ = rinvS[b * K8 + (ke >> 3)];
      } else {
        float sfac = 1.f / (8.f * (float)N);
        float sv = meanS[b * K8 + (ke >> 3)];
        float qv = rinvS[b * K8 + (ke >> 3)];
        m_ = sv * sfac;
        r_ = rsqrtf(qv * sfac - m_ * m_ + 1e-5f);
      }
      float4 g0q = *(const float4*)(gamma + ke);
      float4 g1q = *(const float4*)(gamma + ke + 4);
      float4 e0q = *(const float4*)(beta + ke);
      float4 e1q = *(const float4*)(beta + ke + 4);
      float ga[8] = {g0q.x, g0q.y, g0q.z, g0q.w, g1q.x, g1q.y, g1q.z, g1q.w};
      float bb[8] = {e0q.x, e0q.y, e0q.z, e0q.w, e1q.x, e1q.y, e1q.z, e1q.w};
#pragma unroll
      for (int j = 0; j < 8; ++j) {
        x0[j] = fmaxf((x0[j] - m_) * r_ * ga[j] + bb[j], 0.f);
        x1[j] = fmaxf((x1[j] - m_) * r_ * ga[j] + bb[j], 0.f);
      }
    }
    H8 h0, h1;
#pragma unroll
    for (int j = 0; j < 8; ++j) {
      h0.u[j] = f2bf(x0[j]);
      h1.u[j] = f2bf(x1[j]);
    }
    *(uint4*)&Blds[0][sko][sn][0] = h0.q;
    *(uint4*)&Blds[0][sko][sn + 1][0] = h1.q;
  };

  auto compute = [&](int ab, int bb) {
    bh8 af[4], bfr[4];
#pragma unroll
    for (int mi = 0; mi < 4; ++mi)
      af[mi] = *(const bh8*)(&Alds[ab][klane][wm * 64 + mi * 16 + mlane][0]);
#pragma unroll
    for (int ni = 0; ni < 4; ++ni)
      bfr[ni] = *(const bh8*)(&Blds[bb][klane][wn * 64 + ni * 16 + mlane][0]);
#pragma unroll
    for (int mi = 0; mi < 4; ++mi)
#pragma unroll
      for (int ni = 0; ni < 4; ++ni)
        acc[mi][ni] = __builtin_amdgcn_mfma_f32_16x16x32_bf16(
            af[mi], bfr[ni], acc[mi][ni], 0, 0, 0);
  };

  if (XM == 4) {
    dmaA(0, 0);
    dmaB4(0, 0);
    __syncthreads();
    for (int k0 = 0; k0 < I; k0 += 32) {
      const int cur = (k0 >> 5) & 1;
      if (k0 + 32 < I) {
        dmaA(k0 + 32, cur ^ 1);
        dmaB4(k0 + 32, cur ^ 1);
      }
      compute(cur, cur);
      __syncthreads();
    }
  } else {
    dmaA(0, 0);
    gloadB(0);
    for (int k0 = 0; k0 < I; k0 += 32) {
      const int cur = (k0 >> 5) & 1;
      bstoreB(k0);
      __syncthreads();
      if (k0 + 32 < I) {
        dmaA(k0 + 32, cur ^ 1);
        gloadB(k0 + 32);
      }
      compute(cur, 0);
      __syncthreads();
    }
  }

  // ---- epilogue: vectorized over 4 consecutive o ----
  float sred[4] = {0.f, 0.f, 0.f, 0.f};
  float qred[4] = {0.f, 0.f, 0.f, 0.f};
#pragma unroll
  for (int mi = 0; mi < 4; ++mi) {
    const int o = o0 + wm * 64 + mi * 16 + klane * 4;
    if (o >= O) continue;
    float4 bi;
    if (bias) bi = *(const float4*)(bias + o);
    float4 ra;
    if (RES == 2) ra = *(const float4*)(resA + (size_t)b * O + o);
#pragma unroll
    for (int ni = 0; ni < 4; ++ni) {
      const int n = n0 + wn * 64 + ni * 16 + mlane;
      if (n >= N) continue;
      float v0 = acc[mi][ni][0], v1 = acc[mi][ni][1];
      float v2 = acc[mi][ni][2], v3 = acc[mi][ni][3];
      if (bias) { v0 += bi.x; v1 += bi.y; v2 += bi.z; v3 += bi.w; }
      size_t obase = ((size_t)b * NPn + n) * O + o;
      if (RES == 1) {
        float4 rv = *(const float4*)(resA + obase);
        v0 += rv.x; v1 += rv.y; v2 += rv.z; v3 += rv.w;
      }
      if (RES == 3) {
        ushort4 rv = *(const ushort4*)((const unsigned short*)resA + obase);
        v0 += bf2f(rv.x); v1 += bf2f(rv.y);
        v2 += bf2f(rv.z); v3 += bf2f(rv.w);
      }
      if (RES == 2) {
        float4 rb = *(const float4*)(resB + (size_t)n * O + o);
        v0 += ra.x + rb.x; v1 += ra.y + rb.y;
        v2 += ra.z + rb.z; v3 += ra.w + rb.w;
      }
      if (ORELU) {
        v0 = fmaxf(v0, 0.f); v1 = fmaxf(v1, 0.f);
        v2 = fmaxf(v2, 0.f); v3 = fmaxf(v3, 0.f);
      }
      if (STATS) {
        sred[mi] += v0 + v1 + v2 + v3;
        qred[mi] += v0 * v0 + v1 * v1 + v2 * v2 + v3 * v3;
      }
      if (OUT16) {
        ushort4 h;
        h.x = f2bf(v0); h.y = f2bf(v1); h.z = f2bf(v2); h.w = f2bf(v3);
        *(ushort4*)((unsigned short*)outv + obase) = h;
      } else {
        float4 fv; fv.x = v0; fv.y = v1; fv.z = v2; fv.w = v3;
        *(float4*)((float*)outv + obase) = fv;
      }
    }
  }
  if (STATS) {
    const int G = O >> 3;
#pragma unroll
    for (int mi = 0; mi < 4; ++mi) {
      const int o = o0 + wm * 64 + mi * 16 + klane * 4;
      if (o >= O) continue;
      float s = sred[mi], q = qred[mi];
#pragma unroll
      for (int m = 1; m < 16; m <<= 1) {
        s += __shfl_xor(s, m, 64);
        q += __shfl_xor(q, m, 64);
      }
      if (mlane == 0) {
        atomicAdd(&sacc[b * G + (o >> 3)], s);
        atomicAdd(&qacc[b * G + (o >> 3)], q);
      }
    }
  }
}

// ---------------------------------------------------------------------------
// head kernels
// ---------------------------------------------------------------------------
__global__ __launch_bounds__(THREADS) void h2_k(
    const float* __restrict__ t64, const float* __restrict__ W,
    const float* __restrict__ bias, float* __restrict__ out, int N, int NPn) {
  int gid = blockIdx.x * THREADS + threadIdx.x;
  int o = gid & 31, n = gid >> 5;
  if (n >= N) return;
  int b = blockIdx.y;
  const float* xr = t64 + ((size_t)b * NPn + n) * 64;
  const float* wr = W + o * 64;
  float acc = bias[o];
#pragma unroll
  for (int i = 0; i < 64; i += 4) {
    float4 w4 = *(const float4*)(wr + i);
    float4 x4 = *(const float4*)(xr + i);
    acc += w4.x * x4.x + w4.y * x4.y + w4.z * x4.z + w4.w * x4.w;
  }
  out[((size_t)b * NPn + n) * 32 + o] = acc;
}

__global__ __launch_bounds__(THREADS) void stats_head_k(
    const float* __restrict__ X, float* __restrict__ mean,
    float* __restrict__ rinv, int NPn, int N) {
  int b = blockIdx.x >> 2, g = blockIdx.x & 3;
  int c = g * 8 + (threadIdx.x & 7);
  float s = 0.f, q = 0.f;
  for (int n = threadIdx.x >> 3; n < N; n += 32) {
    float x = X[((size_t)b * NPn + n) * 32 + c];
    s += x; q += x * x;
  }
#pragma unroll
  for (int off = 32; off; off >>= 1) {
    s += __shfl_down(s, off, 64);
    q += __shfl_down(q, off, 64);
  }
  __shared__ float shs[4], shq[4];
  int wv = threadIdx.x >> 6;
  if ((threadIdx.x & 63) == 0) { shs[wv] = s; shq[wv] = q; }
  __syncthreads();
  if (threadIdx.x == 0) {
    s = shs[0] + shs[1] + shs[2] + shs[3];
    q = shq[0] + shq[1] + shq[2] + shq[3];
    float inv = 1.f / (8.f * (float)N);
    float m = s * inv;
    float var = q * inv - m * m;
    mean[blockIdx.x] = m;
    rinv[blockIdx.x] = rsqrtf(var + 1e-5f);
  }
}

__global__ __launch_bounds__(THREADS) void h3_k(
    const float* __restrict__ t32, const float* __restrict__ mean,
    const float* __restrict__ rinv, const float* __restrict__ g,
    const float* __restrict__ be, const float* __restrict__ W,
    const float* __restrict__ bias, float* __restrict__ out, int N, int NPn) {
  int n = blockIdx.x * THREADS + threadIdx.x;
  if (n >= N) return;
  int b = blockIdx.y;
  const float* xr = t32 + ((size_t)b * NPn + n) * 32;
  float y0 = bias[0], y1 = bias[1], y2 = bias[2];
#pragma unroll
  for (int c = 0; c < 32; ++c) {
    float m = mean[b * 4 + (c >> 3)], ri = rinv[b * 4 + (c >> 3)];
    float x = fmaxf((xr[c] - m) * ri * g[c] + be[c], 0.f);
    y0 = fmaf(W[c], x, y0);
    y1 = fmaf(W[32 + c], x, y1);
    y2 = fmaf(W[64 + c], x, y2);
  }
  out[(size_t)b * 3 * N + n] = y0;
  out[(size_t)b * 3 * N + N + n] = y1;
  out[(size_t)b * 3 * N + 2 * N + n] = y2;
}

// ---------------------------------------------------------------------------
extern "C" void kernel_launch(void* const* d_in, const int* in_sizes, int n_in,
                              void* d_out, int out_size, void* d_ws,
                              size_t ws_size, hipStream_t stream) {
  (void)n_in; (void)out_size; (void)ws_size;
  const float* img = (const float*)d_in[0];
  const float* verts = (const float*)d_in[1];
  const int* src = (const int*)d_in[2];
  const float* adjw = (const float*)d_in[4];
  const float* lin0_W = (const float*)d_in[5];
  const float* lin0_b = (const float*)d_in[6];
  const float* b0_pre_g = (const float*)d_in[7];
  const float* b0_pre_b = (const float*)d_in[8];
  const float* b0_lin1_W = (const float*)d_in[9];
  const float* b0_lin1_b = (const float*)d_in[10];
  const float* b0_n1_g = (const float*)d_in[11];
  const float* b0_n1_b = (const float*)d_in[12];
  const float* b0_conv_W = (const float*)d_in[13];
  const float* b0_conv_b = (const float*)d_in[14];
  const float* b0_n2_g = (const float*)d_in[15];
  const float* b0_n2_b = (const float*)d_in[16];
  const float* b0_lin2_W = (const float*)d_in[17];
  const float* b0_lin2_b = (const float*)d_in[18];
  const float* b0_skip_W = (const float*)d_in[19];
  const float* b0_skip_b = (const float*)d_in[20];
  const float* blk_pre_g = (const float*)d_in[21];
  const float* blk_pre_b = (const float*)d_in[22];
  const float* blk_lin1_W = (const float*)d_in[23];
  const float* blk_lin1_b = (const float*)d_in[24];
  const float* blk_n1_g = (const float*)d_in[25];
  const float* blk_n1_b = (const float*)d_in[26];
  const float* blk_conv_W = (const float*)d_in[27];
  const float* blk_conv_b = (const float*)d_in[28];
  const float* blk_n2_g = (const float*)d_in[29];
  const float* blk_n2_b = (const float*)d_in[30];
  const float* blk_lin2_W = (const float*)d_in[31];
  const float* blk_lin2_b = (const float*)d_in[32];
  const float* h1_W = (const float*)d_in[33];
  const float* h1_b = (const float*)d_in[34];
  const float* h2_W = (const float*)d_in[35];
  const float* h2_b = (const float*)d_in[36];
  const float* hn_g = (const float*)d_in[37];
  const float* hn_b = (const float*)d_in[38];
  const float* h3_W = (const float*)d_in[39];
  const float* h3_b = (const float*)d_in[40];

  const int N = in_sizes[1] / 3;           // 1723
  const int NP = ((N + 127) / 128) * 128;  // 1792
  const int NT128 = NP / 128;              // 14
  const int B = 16;

  char* wsb = (char*)d_ws;
  size_t off = 0;
  auto alloc = [&](size_t nbytes) {
    void* p = wsb + off;
    off += (nbytes + 255) & ~(size_t)255;
    return p;
  };
  unsigned short* xb16 = (unsigned short*)alloc((size_t)B * NP * 512 * 2);
  unsigned short* t256a = (unsigned short*)alloc((size_t)B * NP * 256 * 2);
  unsigned short* t256b = (unsigned short*)alloc((size_t)B * NP * 256 * 2);
  float* vbuf = (float*)alloc((size_t)NP * 1024 * 4);
  float* svbuf = (float*)alloc((size_t)NP * 512 * 4);
  float* t64 = (float*)alloc((size_t)B * NP * 64 * 4);
  float* t32 = (float*)alloc((size_t)B * NP * 32 * 4);
  float* imgT = (float*)alloc(2048 * 16 * 4);
  float* wv = (float*)alloc(3 * 1024 * 4);
  float* m0 = (float*)alloc(2048 * 4);
  float* r0 = (float*)alloc(2048 * 4);
  float* mh = (float*)alloc(64 * 4);
  float* rh = (float*)alloc(64 * 4);
  // one zero-initialized region: GN s/ss + vstats sv/sq + ub + suT
  float* zerobuf = (float*)alloc((size_t)49152 * 4);
  float* sA = zerobuf;
  float* qA = zerobuf + 11264;
  float* sv = zerobuf + 22528;
  float* sq = zerobuf + 23552;
  float* ub = zerobuf + 24576;   // 16*1024
  float* suT = zerobuf + 40960;  // 16*512
  const int off_b0n1 = 0, off_b0n2 = 512;
  auto off_pre = [](int l) { return 1024 + l * 2048; };
  auto off_n1 = [](int l) { return 1024 + l * 2048 + 1024; };
  auto off_n2 = [](int l) { return 1024 + l * 2048 + 1536; };
  // packed weights (128-o tile layout)
  unsigned short* pw_b0l1 = (unsigned short*)alloc(262144 * 2);
  unsigned short* pw_b0cv = (unsigned short*)alloc(65536 * 2);
  unsigned short* pw_b0l2 = (unsigned short*)alloc(131072 * 2);
  unsigned short* pw_b0sk = (unsigned short*)alloc(524288 * 2);
  unsigned short* pw_l1 = (unsigned short*)alloc(655360 * 2);
  unsigned short* pw_cv = (unsigned short*)alloc(327680 * 2);
  unsigned short* pw_l2 = (unsigned short*)alloc(655360 * 2);
  unsigned short* pw_h1 = (unsigned short*)alloc(65536 * 2);

  dim3 blk(THREADS);
  auto cdiv = [](size_t a, size_t b) { return (unsigned)((a + b - 1) / b); };

  hipMemsetAsync(zerobuf, 0, (size_t)49152 * 4, stream);

  // ---- merged weight packing (one launch, 128-o-tile layout) ----
  {
    PackArgs pa;
    unsigned c = 0;
    auto set = [&](int i, const float* W, unsigned short* o, int O, int K,
                   int TW, int nOt, unsigned tot) {
      pa.d[i] = {W, o, O, K, TW, nOt, c};
      c += tot;
    };
    set(0, b0_lin1_W, pw_b0l1, 256, 1024, 0, 2, 262144);
    set(1, b0_conv_W, pw_b0cv, 256, 256, 1, 2, 65536);
    set(2, b0_lin2_W, pw_b0l2, 512, 256, 0, 4, 131072);
    set(3, b0_skip_W, pw_b0sk, 512, 1024, 0, 4, 524288);
    set(4, blk_lin1_W, pw_l1, 256, 512, 0, 2, 655360);
    set(5, blk_conv_W, pw_cv, 256, 256, 1, 2, 327680);
    set(6, blk_lin2_W, pw_l2, 512, 256, 0, 4, 655360);
    set(7, h1_W, pw_h1, 64, 512, 0, 1, 65536);
    pa.grand = c;
    packall_k<<<cdiv(pa.grand, THREADS), blk, 0, stream>>>(pa);
  }

  // ---- lin0 decomposition ----
  transpose_img_k<<<cdiv(2048 * 16, THREADS), blk, 0, stream>>>(img, imgT);
  pack_wv_k<<<cdiv(3072, THREADS), blk, 0, stream>>>(lin0_W, wv);
  ugemm2_k<<<dim3(64, 16), blk, 0, stream>>>(lin0_W, 2051, 3, lin0_b, imgT,
                                             ub, 2048, 1024, 0, 128);
  vertproj_k<<<cdiv((size_t)N * 1024, THREADS), blk, 0, stream>>>(wv, verts, vbuf, N);

  const dim3 aggGrid(cdiv(N, 4), 16);

  // ---- block b0 ----
  vstats_k<<<dim3(4, 16), blk, 0, stream>>>(vbuf, sv, sq, N);
  combine_b0_k<<<dim3(8), blk, 0, stream>>>(ub, sv, sq, m0, r0, N);
  mgemm_k<1, 0, 1, 0, 1><<<dim3(NT128, 2, 16), blk, 0, stream>>>(
      pw_b0l1, b0_lin1_b, nullptr, ub, vbuf, m0, r0, b0_pre_g, b0_pre_b,
      nullptr, nullptr, sA + off_b0n1, qA + off_b0n1, t256a, 256, 1024, N, NP);
  ugemm2_k<<<dim3(32, 8), blk, 0, stream>>>(b0_skip_W, 1024, 0, b0_skip_b, ub,
                                            suT, 1024, 512, 1, 128);
  mgemm_k<0, 0, 0, 0, 0><<<dim3(NT128, 4, 1), blk, 0, stream>>>(
      pw_b0sk, nullptr, vbuf, nullptr, nullptr, nullptr, nullptr, nullptr,
      nullptr, nullptr, nullptr, nullptr, nullptr, svbuf, 512, 1024, N, NP);
  agg16_k<<<aggGrid, blk, 0, stream>>>(t256a, sA + off_b0n1, qA + off_b0n1,
                                       b0_n1_g, b0_n1_b, src, adjw, t256b, N, NP);
  mgemm_k<4, 0, 1, 0, 1><<<dim3(NT128, 2, 16), blk, 0, stream>>>(
      pw_b0cv, b0_conv_b, t256b, nullptr, nullptr, nullptr, nullptr, nullptr,
      nullptr, nullptr, nullptr, sA + off_b0n2, qA + off_b0n2, t256a, 256, 256,
      N, NP);
  // b0 lin2: decomposed skip residual, bf16-only output stream
  mgemm_k<3, 2, 1, 0, 1><<<dim3(NT128, 4, 16), blk, 0, stream>>>(
      pw_b0l2, b0_lin2_b, t256a, nullptr, nullptr, sA + off_b0n2,
      qA + off_b0n2, b0_n2_g, b0_n2_b, suT, svbuf, sA + off_pre(0),
      qA + off_pre(0), xb16, 512, 256, N, NP);

  // ---- blocks 1..5 ----
  for (int l = 0; l < 5; ++l) {
    const float* pg = blk_pre_g + l * 512;
    const float* pb = blk_pre_b + l * 512;
    const unsigned short* l1W = pw_l1 + (size_t)l * 131072;
    const float* l1b = blk_lin1_b + l * 256;
    const float* n1g = blk_n1_g + l * 256;
    const float* n1b = blk_n1_b + l * 256;
    const unsigned short* cW = pw_cv + (size_t)l * 65536;
    const float* cb = blk_conv_b + l * 256;
    const float* n2g = blk_n2_g + l * 256;
    const float* n2b = blk_n2_b + l * 256;
    const unsigned short* l2W = pw_l2 + (size_t)l * 131072;
    const float* l2b = blk_lin2_b + l * 512;

    mgemm_k<3, 0, 1, 0, 1><<<dim3(NT128, 2, 16), blk, 0, stream>>>(
        l1W, l1b, xb16, nullptr, nullptr, sA + off_pre(l), qA + off_pre(l), pg,
        pb, nullptr, nullptr, sA + off_n1(l), qA + off_n1(l), t256a, 256, 512,
        N, NP);
    agg16_k<<<aggGrid, blk, 0, stream>>>(t256a, sA + off_n1(l), qA + off_n1(l),
                                         n1g, n1b, src, adjw, t256b, N, NP);
    mgemm_k<4, 0, 1, 0, 1><<<dim3(NT128, 2, 16), blk, 0, stream>>>(
        cW, cb, t256b, nullptr, nullptr, nullptr, nullptr, nullptr, nullptr,
        nullptr, nullptr, sA + off_n2(l), qA + off_n2(l), t256a, 256, 256, N, NP);
    if (l < 4) {
      mgemm_k<3, 3, 1, 0, 1><<<dim3(NT128, 4, 16), blk, 0, stream>>>(
          l2W, l2b, t256a, nullptr, nullptr, sA + off_n2(l), qA + off_n2(l),
          n2g, n2b, (const float*)xb16, nullptr, sA + off_pre(l + 1),
          qA + off_pre(l + 1), xb16, 512, 256, N, NP);
    } else {
      mgemm_k<3, 3, 1, 0, 0><<<dim3(NT128, 4, 16), blk, 0, stream>>>(
          l2W, l2b, t256a, nullptr, nullptr, sA + off_n2(l), qA + off_n2(l),
          n2g, n2b, (const float*)xb16, nullptr, nullptr, nullptr, xb16, 512,
          256, N, NP);
    }
  }

  // ---- head ----
  mgemm_k<4, 0, 0, 1, 0><<<dim3(NT128, 1, 16), blk, 0, stream>>>(
      pw_h1, h1_b, xb16, nullptr, nullptr, nullptr, nullptr, nullptr, nullptr,
      nullptr, nullptr, nullptr, nullptr, t64, 64, 512, N, NP);
  h2_k<<<dim3(cdiv((size_t)N * 32, THREADS), 16), blk, 0, stream>>>(
      t64, h2_W, h2_b, t32, N, NP);
  stats_head_k<<<dim3(64), blk, 0, stream>>>(t32, mh, rh, NP, N);
  h3_k<<<dim3(cdiv(N, THREADS), 16), blk, 0, stream>>>(
      t32, mh, rh, hn_g, hn_b, h3_W, h3_b, (float*)d_out, N, NP);
}